// Round 17
// baseline (49.937 us; speedup 1.0000x reference)
//
#include <hip/hip_runtime.h>
#include <hip/hip_bf16.h>
#include <stdint.h>

#define N_ROWS 16384
#define O_ROWS 1024
#define K_DIM  512

typedef __bf16 bf16x8 __attribute__((ext_vector_type(8)));
typedef float  f32x4  __attribute__((ext_vector_type(4)));

__device__ __forceinline__ ushort f2bfu(float f) {
    __bf16 h = (__bf16)f;
    return __builtin_bit_cast(ushort, h);
}

// lgkm-only barrier (proven safe r14/r15/r16): drains LDS ops, leaves global
// loads in flight across the barrier.
#define BAR_LGKM()  do {                                        \
    asm volatile("s_waitcnt lgkmcnt(0)" ::: "memory");          \
    __builtin_amdgcn_s_barrier();                               \
} while (0)

// ---------------------------------------------------------------------------
// Round 17 = round 16 (256x128 tile, 40.6us) + the r12-proven register
// prefetch: next K-tile's 6 f32x4x2 loads (48 VGPR) issued before the
// barrier, consumed next iteration -- HBM latency hides under MFMA phase.
// Tests prefetch-vs-occupancy (unified regs ~175 -> 1 blk/CU vs r16's 2).
//  - 512 thr, 8 waves (4x2), 64x64 wave tiles, acc 4x4 (AGPR), LDS 48 KB.
//  - T2 XOR-swizzle, bijective XCD swizzle (512 blocks), extended-K-tile
//    epilogue, #pragma unroll 1 on kt (r10 spill lesson).
// ---------------------------------------------------------------------------
__global__ __launch_bounds__(512) void quadra_kernel(
    const float* __restrict__ x, const float* __restrict__ mean,
    float* __restrict__ out)
{
    __shared__ ushort sA[256 * 64];   // [row][k] bf16 (swizzled), 32 KiB
    __shared__ ushort sB[128 * 64];   // [orow][k] bf16 -2*mean (swizzled), 16 KiB

    const int bid  = blockIdx.x;                // 0..511
    const int t    = (bid & 7) * 64 + (bid >> 3);
    const int brow = (t >> 3) * 256;
    const int bcol = (t & 7) * 128;

    const int tid  = threadIdx.x;
    const int lane = tid & 63;
    const int wid  = tid >> 6;                  // 0..7
    const int wr = wid >> 1, wc = wid & 1;      // 4x2 wave grid, 64x64 out each

    f32x4 acc[4][4] = {};

    // staging: r0 = tid>>3 (0..63), q = tid&7 (k-octet).
    // thread stages A rows {r0+64i : i=0..3}, B rows {r0+64i : i=0..1}.
    const int r0 = tid >> 3;
    const int q  = tid & 7;

    const float* gA = x    + (size_t)(brow + r0) * K_DIM + q * 8;
    const float* gB = mean + (size_t)(bcol + r0) * K_DIM + q * 8;

    float asq[4] = {0.f, 0.f, 0.f, 0.f};
    float bsq[2] = {0.f, 0.f};

    const int hi = lane >> 4, cl = lane & 15;

    // prologue prefetch (kt = 0): 4 A rows + 2 B rows, 8 floats each
    f32x4 pa[4][2], pb[2][2];
    #pragma unroll
    for (int i = 0; i < 4; ++i) {
        const float* p = gA + (size_t)(i * 64) * K_DIM;
        pa[i][0] = *(const f32x4*)(p);
        pa[i][1] = *(const f32x4*)(p + 4);
    }
    #pragma unroll
    for (int i = 0; i < 2; ++i) {
        const float* p = gB + (size_t)(i * 64) * K_DIM;
        pb[i][0] = *(const f32x4*)(p);
        pb[i][1] = *(const f32x4*)(p + 4);
    }

    #pragma unroll 1
    for (int kt = 0; kt < 8; ++kt) {
        // --- consume prefetched A (4 rows/thread) ---
        #pragma unroll
        for (int i = 0; i < 4; ++i) {
            f32x4 v0 = pa[i][0], v1 = pa[i][1];
            asq[i] += v0[0]*v0[0] + v0[1]*v0[1] + v0[2]*v0[2] + v0[3]*v0[3]
                    + v1[0]*v1[0] + v1[1]*v1[1] + v1[2]*v1[2] + v1[3]*v1[3];
            bf16x8 cv;
            cv[0] = (__bf16)v0[0]; cv[1] = (__bf16)v0[1];
            cv[2] = (__bf16)v0[2]; cv[3] = (__bf16)v0[3];
            cv[4] = (__bf16)v1[0]; cv[5] = (__bf16)v1[1];
            cv[6] = (__bf16)v1[2]; cv[7] = (__bf16)v1[3];
            const int row = r0 + i * 64;
            const int wb  = (q * 16) ^ ((row & 7) << 4);
            *(bf16x8*)(sA + row * 64 + (wb >> 1)) = cv;
        }
        // --- consume prefetched B (2 rows/thread), scaled by -2 ---
        #pragma unroll
        for (int i = 0; i < 2; ++i) {
            f32x4 v0 = pb[i][0], v1 = pb[i][1];
            bsq[i] += v0[0]*v0[0] + v0[1]*v0[1] + v0[2]*v0[2] + v0[3]*v0[3]
                    + v1[0]*v1[0] + v1[1]*v1[1] + v1[2]*v1[2] + v1[3]*v1[3];
            bf16x8 cv;
            cv[0] = (__bf16)(v0[0] * -2.0f); cv[1] = (__bf16)(v0[1] * -2.0f);
            cv[2] = (__bf16)(v0[2] * -2.0f); cv[3] = (__bf16)(v0[3] * -2.0f);
            cv[4] = (__bf16)(v1[0] * -2.0f); cv[5] = (__bf16)(v1[1] * -2.0f);
            cv[6] = (__bf16)(v1[2] * -2.0f); cv[7] = (__bf16)(v1[3] * -2.0f);
            const int row = r0 + i * 64;
            const int wb  = (q * 16) ^ ((row & 7) << 4);
            *(bf16x8*)(sB + row * 64 + (wb >> 1)) = cv;
        }

        // issue next-tile loads: in flight across BAR + MFMA phase + bar2
        if (kt < 7) {
            #pragma unroll
            for (int i = 0; i < 4; ++i) {
                const float* p = gA + (size_t)(i * 64) * K_DIM + (kt + 1) * 64;
                pa[i][0] = *(const f32x4*)(p);
                pa[i][1] = *(const f32x4*)(p + 4);
            }
            #pragma unroll
            for (int i = 0; i < 2; ++i) {
                const float* p = gB + (size_t)(i * 64) * K_DIM + (kt + 1) * 64;
                pb[i][0] = *(const f32x4*)(p);
                pb[i][1] = *(const f32x4*)(p + 4);
            }
        }

        BAR_LGKM();   // staging visible; prefetch stays in flight

        #pragma unroll
        for (int ks = 0; ks < 2; ++ks) {
            bf16x8 a[4], b[4];
            #pragma unroll
            for (int m = 0; m < 4; ++m) {
                const int row = wr*64 + m*16 + cl;
                const int rb  = (ks*64 + hi*16) ^ ((row & 7) << 4);
                a[m] = *(const bf16x8*)(sA + row * 64 + (rb >> 1));
            }
            #pragma unroll
            for (int n = 0; n < 4; ++n) {
                const int row = wc*64 + n*16 + cl;
                const int rb  = (ks*64 + hi*16) ^ ((row & 7) << 4);
                b[n] = *(const bf16x8*)(sB + row * 64 + (rb >> 1));
            }
            #pragma unroll
            for (int m = 0; m < 4; ++m)
                #pragma unroll
                for (int n = 0; n < 4; ++n)
                    acc[m][n] = __builtin_amdgcn_mfma_f32_16x16x32_bf16(
                        a[m], b[n], acc[m][n], 0, 0, 0);
        }

        BAR_LGKM();   // reads done; next kt may overwrite
    }

    // Extended K-tile (aliased into sA, dead after the loop):
    //   sAe[row(256)] = [xsq, 1, 0 x30]   sBe[row(128)] = [1, msq, 0 x30]
    ushort* sAe = sA;              // 256*32 = 16 KB
    ushort* sBe = sA + 256 * 32;   // 128*32 =  8 KB
    #pragma unroll
    for (int i = 0; i < 4; ++i) {
        float sa = asq[i];
        #pragma unroll
        for (int msk = 1; msk < 8; msk <<= 1) sa += __shfl_xor(sa, msk);
        uint2 aw = {0u, 0u};
        if (q == 0) aw.x = (uint32_t)f2bfu(sa) | (0x3F80u << 16);  // [xsq, 1.0]
        *(uint2*)(sAe + (r0 + i * 64) * 32 + q * 4) = aw;
    }
    #pragma unroll
    for (int i = 0; i < 2; ++i) {
        float sb = bsq[i];
        #pragma unroll
        for (int msk = 1; msk < 8; msk <<= 1) sb += __shfl_xor(sb, msk);
        uint2 bw = {0u, 0u};
        if (q == 0) bw.x = 0x3F80u | ((uint32_t)f2bfu(sb) << 16);  // [1.0, msq]
        *(uint2*)(sBe + (r0 + i * 64) * 32 + q * 4) = bw;
    }
    BAR_LGKM();

    {   // extra MFMA: adds xsq[r] + msq[o] into every accumulator element
        bf16x8 a[4], b[4];
        #pragma unroll
        for (int m = 0; m < 4; ++m)
            a[m] = *(const bf16x8*)(sAe + (wr*64 + m*16 + cl) * 32 + hi * 8);
        #pragma unroll
        for (int n = 0; n < 4; ++n)
            b[n] = *(const bf16x8*)(sBe + (wc*64 + n*16 + cl) * 32 + hi * 8);
        #pragma unroll
        for (int m = 0; m < 4; ++m)
            #pragma unroll
            for (int n = 0; n < 4; ++n)
                acc[m][n] = __builtin_amdgcn_mfma_f32_16x16x32_bf16(
                    a[m], b[n], acc[m][n], 0, 0, 0);
    }

    // epilogue: C/D layout col = lane&15, row = (lane>>4)*4 + j
    const int rg = lane >> 4;
    #pragma unroll
    for (int m = 0; m < 4; ++m) {
        #pragma unroll
        for (int j = 0; j < 4; ++j) {
            const int grow = brow + wr*64 + m*16 + rg*4 + j;
            float* orow = out + (size_t)grow * O_ROWS + bcol + wc*64 + cl;
            #pragma unroll
            for (int n = 0; n < 4; ++n)
                orow[n * 16] = rsqrtf(acc[m][n][j]);
        }
    }
}

extern "C" void kernel_launch(void* const* d_in, const int* in_sizes, int n_in,
                              void* d_out, int out_size, void* d_ws, size_t ws_size,
                              hipStream_t stream) {
    const float* x    = (const float*)d_in[0];
    const float* mean = (const float*)d_in[1];
    float* out = (float*)d_out;

    quadra_kernel<<<dim3((N_ROWS / 256) * (O_ROWS / 128)), 512, 0, stream>>>(
        x, mean, out);
}